// Round 8
// baseline (354.376 us; speedup 1.0000x reference)
//
#include <hip/hip_runtime.h>
#include <hip/hip_bf16.h>

// Problem constants (B,S,E,H,L,DFF) = (2,2048,512,8,2,2048), D=64
constexpr int BB   = 2;
constexpr int SS   = 2048;
constexpr int EE   = 512;
constexpr int HH   = 8;
constexpr int DD   = 64;
constexpr int DFF_ = 2048;
constexpr int NTOK = BB * SS;          // 4096 tokens
constexpr int NE   = NTOK * EE;        // 2097152
constexpr float EPSF  = 1e-5f;
constexpr float SCL2  = 0.125f * 1.44269504088896f;  // 1/sqrt(D) * log2(e)
constexpr float MBIAS = -1e30f;
constexpr int KSPLIT = 2;              // attention split-K parts (R3-proven)
constexpr int KHALF  = SS / KSPLIT;    // 1024 kv per block

typedef __bf16 v8bf __attribute__((ext_vector_type(8)));
typedef __bf16 v4bf __attribute__((ext_vector_type(4)));
typedef float  v4f  __attribute__((ext_vector_type(4)));
typedef unsigned int v4u __attribute__((ext_vector_type(4)));

__device__ __forceinline__ float bf2f(unsigned short u) {
    return __uint_as_float(((unsigned int)u) << 16);
}
__device__ __forceinline__ float bf2f(__bf16 u) {
    unsigned short us = __builtin_bit_cast(unsigned short, u);
    return __uint_as_float(((unsigned int)us) << 16);
}
// adaptive load: f=1 -> float32 buffer, f=0 -> bf16 buffer
__device__ __forceinline__ float ldA(const void* p, size_t i, int f) {
    return f ? ((const float*)p)[i] : bf2f(((const unsigned short*)p)[i]);
}
// async global->LDS, 16 B per lane (m97-verified path)
__device__ __forceinline__ void gll16(const void* g, void* l) {
    __builtin_amdgcn_global_load_lds(
        (const __attribute__((address_space(1))) void*)g,
        (__attribute__((address_space(3))) void*)l, 16, 0, 0);
}
// pack 2 f32 -> 1 dword of 2 bf16 (lo=a, hi=b) in ONE instruction.
__device__ __forceinline__ unsigned cvtpk(float a, float b) {
    unsigned r;
    asm("v_cvt_pk_bf16_f32 %0, %1, %2" : "=v"(r) : "v"(a), "v"(b));
    return r;
}
// raw v_exp_f32 (R20-proven: kills the OCML exp2f fixup path)
__device__ __forceinline__ float fexp2(float x) {
#if __has_builtin(__builtin_amdgcn_exp2f)
    return __builtin_amdgcn_exp2f(x);
#else
    return exp2f(x);
#endif
}

// --------------------------------------------------------------- cvt x -> f32 fused with layer-0 LN1
// Self-sniffing (R17): each block decides dtype locally; block 0 publishes
// the flag for all later (stream-ordered) dispatches.
__global__ __launch_bounds__(256) void cvt_ln(
    const void* __restrict__ in, float* __restrict__ X,
    const void* __restrict__ g, const void* __restrict__ b,
    __bf16* __restrict__ Hb, int* __restrict__ flagw)
{
    const int row = blockIdx.x, t = threadIdx.x;
    __shared__ float red[8], st[2];
    __shared__ int scnt[4], sflag;
    {
        const unsigned short* u = (const unsigned short*)in;
        int bad = 0;
        #pragma unroll
        for (int i = 0; i < 2; ++i) {
            float v = bf2f(u[t + 256 * i]);
            if (!(fabsf(v) < 1000.f)) bad++;
        }
        #pragma unroll
        for (int off = 32; off > 0; off >>= 1) bad += __shfl_down(bad, off, 64);
        if ((t & 63) == 0) scnt[t >> 6] = bad;
        __syncthreads();
        if (t == 0) sflag = (scnt[0] + scnt[1] + scnt[2] + scnt[3] > 1) ? 1 : 0;
        __syncthreads();
    }
    const int f = sflag;
    if (row == 0 && t == 0) *flagw = f;

    const size_t i0 = (size_t)row * EE + t, i1 = i0 + 256;
    float v0 = ldA(in, i0, f);
    float v1 = ldA(in, i1, f);
    float s = v0 + v1, q = v0 * v0 + v1 * v1;
    #pragma unroll
    for (int off = 32; off > 0; off >>= 1) {
        s += __shfl_down(s, off, 64);
        q += __shfl_down(q, off, 64);
    }
    const int wid = t >> 6;
    if ((t & 63) == 0) { red[wid] = s; red[4 + wid] = q; }
    __syncthreads();
    if (t == 0) {
        float S_ = red[0] + red[1] + red[2] + red[3];
        float Q_ = red[4] + red[5] + red[6] + red[7];
        float mu = S_ / EE;
        st[0] = mu;
        st[1] = rsqrtf(Q_ / EE - mu * mu + EPSF);
    }
    __syncthreads();
    const float mu = st[0], rs = st[1];
    float o0 = (v0 - mu) * rs * ldA(g, t, f)       + ldA(b, t, f);
    float o1 = (v1 - mu) * rs * ldA(g, t + 256, f) + ldA(b, t + 256, f);
    X[i0] = v0; X[i1] = v1;
    Hb[i0] = (__bf16)o0; Hb[i1] = (__bf16)o1;
}

// --------------------------------------------------------------- all weights -> bf16 (one launch)
__global__ void wcvt_all(const void* __restrict__ wq, const void* __restrict__ wk,
                         const void* __restrict__ wv, const void* __restrict__ W1,
                         const void* __restrict__ W2, __bf16* __restrict__ out,
                         const int* __restrict__ flagp) {
    const int f = *flagp;
    const int i = (blockIdx.x * blockDim.x + threadIdx.x) * 8;
    constexpr int n1 = 2 * EE * EE;      // 524288 per QKV tensor
    constexpr int nf = DFF_ * EE;        // 1048576 per FFN tensor
    const void* src; int off;
    if      (i < n1)          { src = wq; off = i; }
    else if (i < 2 * n1)      { src = wk; off = i - n1; }
    else if (i < 3 * n1)      { src = wv; off = i - 2 * n1; }
    else if (i < 3 * n1 + nf) { src = W1; off = i - 3 * n1; }
    else                      { src = W2; off = i - 3 * n1 - nf; }
    if (f) {
        const float* p = (const float*)src + off;
        #pragma unroll
        for (int j = 0; j < 8; ++j) out[i + j] = (__bf16)p[j];
    } else {
        *(uint4*)(out + i) = *(const uint4*)((const unsigned short*)src + off);
    }
}

// --------------------------------------------------------------- layernorm (single)
__global__ __launch_bounds__(256) void ln_kernel(
    const float* __restrict__ src,
    const void* __restrict__ g, const void* __restrict__ b,
    __bf16* __restrict__ dstb, void* __restrict__ outp,
    const int* __restrict__ flagp)
{
    const int f = *flagp;
    const int row = blockIdx.x, t = threadIdx.x;
    const float* x = src + (size_t)row * EE;
    float v0 = x[t], v1 = x[t + 256];
    float s = v0 + v1, q = v0 * v0 + v1 * v1;
    #pragma unroll
    for (int off = 32; off > 0; off >>= 1) {
        s += __shfl_down(s, off, 64);
        q += __shfl_down(q, off, 64);
    }
    __shared__ float red[8], st[2];
    const int wid = t >> 6;
    if ((t & 63) == 0) { red[wid] = s; red[4 + wid] = q; }
    __syncthreads();
    if (t == 0) {
        float S_ = red[0] + red[1] + red[2] + red[3];
        float Q_ = red[4] + red[5] + red[6] + red[7];
        float mu = S_ / EE;
        st[0] = mu;
        st[1] = rsqrtf(Q_ / EE - mu * mu + EPSF);
    }
    __syncthreads();
    const float mu = st[0], rs = st[1];
    float o0 = (v0 - mu) * rs, o1 = (v1 - mu) * rs;
    if (g) {
        o0 = o0 * ldA(g, t, f)       + ldA(b, t, f);
        o1 = o1 * ldA(g, t + 256, f) + ldA(b, t + 256, f);
    }
    const size_t i0 = (size_t)row * EE + t, i1 = i0 + 256;
    if (dstb) { dstb[i0] = (__bf16)o0; dstb[i1] = (__bf16)o1; }
    if (outp) {
        if (f) { ((float*)outp)[i0] = o0; ((float*)outp)[i1] = o1; }
        else {
            ((__hip_bfloat16*)outp)[i0] = __float2bfloat16(o0);
            ((__hip_bfloat16*)outp)[i1] = __float2bfloat16(o1);
        }
    }
}

// --------------------------------------------------------------- combine + residual + double LN
__global__ __launch_bounds__(256) void combine_ln(
    const __bf16* __restrict__ Opart, const float* __restrict__ MLl,
    const void* __restrict__ g2, const void* __restrict__ b2,
    float* __restrict__ X, __bf16* __restrict__ Hb,
    const int* __restrict__ flagp)
{
    const int f = *flagp;
    const int tok = blockIdx.x, t = threadIdx.x;
    const int b = tok >> 11, s_ = tok & 2047;
    __shared__ float cinv[8];
    __shared__ float red[8], st[2];
    if (t < 8) {
        float l = 0.f;
        #pragma unroll
        for (int zz = 0; zz < KSPLIT; ++zz)
            l += MLl[(size_t)(zz * 16 + b * 8 + t) * SS + s_];
        cinv[t] = (l > 0.f) ? 1.f / l : 0.f;
    }
    __syncthreads();
    float a0 = 0.f, a1 = 0.f;
    {
        int c = t, h = c >> 6, d = c & 63;
        #pragma unroll
        for (int zz = 0; zz < KSPLIT; ++zz)
            a0 += bf2f(Opart[((size_t)(zz * 16 + b * 8 + h) * SS + s_) * 64 + d]);
        a0 *= cinv[h];
        c = t + 256; h = c >> 6; d = c & 63;
        #pragma unroll
        for (int zz = 0; zz < KSPLIT; ++zz)
            a1 += bf2f(Opart[((size_t)(zz * 16 + b * 8 + h) * SS + s_) * 64 + d]);
        a1 *= cinv[h];
    }
    const int wid = t >> 6;
    {
        float s = a0 + a1, q = a0 * a0 + a1 * a1;
        #pragma unroll
        for (int off = 32; off > 0; off >>= 1) {
            s += __shfl_down(s, off, 64);
            q += __shfl_down(q, off, 64);
        }
        if ((t & 63) == 0) { red[wid] = s; red[4 + wid] = q; }
    }
    __syncthreads();
    if (t == 0) {
        float S_ = red[0] + red[1] + red[2] + red[3];
        float Q_ = red[4] + red[5] + red[6] + red[7];
        float mu = S_ / EE;
        st[0] = mu;
        st[1] = rsqrtf(Q_ / EE - mu * mu + EPSF);
    }
    __syncthreads();
    const float mu1 = st[0], rs1 = st[1];
    const size_t i0 = (size_t)tok * EE + t, i1 = i0 + 256;
    float l0v = (a0 - mu1) * rs1 * ldA(g2, t, f)       + ldA(b2, t, f);
    float l1v = (a1 - mu1) * rs1 * ldA(g2, t + 256, f) + ldA(b2, t + 256, f);
    float x0 = X[i0] + l0v, x1 = X[i1] + l1v;
    __syncthreads();
    {
        float s = x0 + x1, q = x0 * x0 + x1 * x1;
        #pragma unroll
        for (int off = 32; off > 0; off >>= 1) {
            s += __shfl_down(s, off, 64);
            q += __shfl_down(q, off, 64);
        }
        if ((t & 63) == 0) { red[wid] = s; red[4 + wid] = q; }
    }
    __syncthreads();
    if (t == 0) {
        float S_ = red[0] + red[1] + red[2] + red[3];
        float Q_ = red[4] + red[5] + red[6] + red[7];
        float mu = S_ / EE;
        st[0] = mu;
        st[1] = rsqrtf(Q_ / EE - mu * mu + EPSF);
    }
    __syncthreads();
    const float mu2 = st[0], rs2 = st[1];
    X[i0] = x0; X[i1] = x1;
    Hb[i0] = (__bf16)((x0 - mu2) * rs2);
    Hb[i1] = (__bf16)((x1 - mu2) * rs2);
}

// --------------------------------------------------------------- MFMA GEMM (NT), 128x128, double-buffered
// BK=64 + both-sides XOR swizzle (R16). Used by FFN1/FFN2 (exact 2 blocks/CU).
__global__ __launch_bounds__(256) void gemm_mfma(
    const __bf16* __restrict__ A,
    const __bf16* Wa, const __bf16* Wb, const __bf16* Wc,
    const void* ba, const void* bb, const void* bc,
    __bf16* oa, __bf16* ob, __bf16* oc,
    float* __restrict__ Cf,
    int M, int N, int K, int flags,
    size_t welem_off, size_t belem_off, const int* __restrict__ flagp)
{
    const int f = *flagp;
    const int z = blockIdx.z;
    const __bf16* W = (z == 0) ? Wa : (z == 1) ? Wb : Wc;
    const void* bias = (z == 0) ? ba : (z == 1) ? bb : bc;
    __bf16* Cb = (z == 0) ? oa : (z == 1) ? ob : oc;
    W += welem_off;
    int kbeg = 0, kend = K;
    if (flags & 4) {
        const int ks = K >> 2;
        kbeg = z * ks; kend = kbeg + ks;
        if (z != 0) bias = nullptr;
    }

    __shared__ __bf16 As[2][128 * 64];   // 2 x 16 KB
    __shared__ __bf16 Bs[2][128 * 64];   // 2 x 16 KB  (64 KB total -> 2 blocks/CU)
    const int t = threadIdx.x;
    const int w = t >> 6, lane = t & 63;
    const int quad = lane >> 4, l16 = lane & 15;
    const int wr = w >> 1, wc = w & 1;
    const int bm = blockIdx.x * 128, bn = blockIdx.y * 128;

    v4f acc[4][4] = {};

    #define STAGE_TILE(dst, src, rowbase, kk)                                   \
        _Pragma("unroll")                                                       \
        for (int ii = 0; ii < 4; ++ii) {                                        \
            const int c  = t + 256 * ii;                                        \
            const int r  = c >> 3, cc = c & 7;                                  \
            const int es = ((cc ^ (r & 7)) * 8);                                \
            gll16(src + (size_t)(rowbase + r) * K + kk + es,                    \
                  (char*)(dst) + c * 16);                                       \
        }

    STAGE_TILE(As[0], A, bm, kbeg)
    STAGE_TILE(Bs[0], W, bn, kbeg)

    int p = 0;
    for (int k0 = kbeg; k0 < kend; k0 += 64) {
        __syncthreads();
        if (k0 + 64 < kend) {
            const int kn = k0 + 64, q_ = p ^ 1;
            STAGE_TILE(As[q_], A, bm, kn)
            STAGE_TILE(Bs[q_], W, bn, kn)
        }
        #pragma unroll
        for (int ks = 0; ks < 2; ++ks) {
            v8bf af[4], bfr[4];
            #pragma unroll
            for (int i = 0; i < 4; ++i) {
                const int row = wr * 64 + i * 16 + l16;
                const int ph  = (quad + ks * 4) ^ (row & 7);
                af[i] = *(const v8bf*)&As[p][row * 64 + ph * 8];
            }
            #pragma unroll
            for (int j = 0; j < 4; ++j) {
                const int row = wc * 64 + j * 16 + l16;
                const int ph  = (quad + ks * 4) ^ (row & 7);
                bfr[j] = *(const v8bf*)&Bs[p][row * 64 + ph * 8];
            }
            #pragma unroll
            for (int i = 0; i < 4; ++i)
                #pragma unroll
                for (int j = 0; j < 4; ++j)
                    acc[i][j] = __builtin_amdgcn_mfma_f32_16x16x32_bf16(
                        af[i], bfr[j], acc[i][j], 0, 0, 0);
        }
        p ^= 1;
    }
    #undef STAGE_TILE

    float bvv[4];
    #pragma unroll
    for (int j = 0; j < 4; ++j) {
        int col = bn + wc * 64 + j * 16 + l16;
        bvv[j] = bias ? ldA(bias, belem_off + col, f) : 0.f;
    }

    #pragma unroll
    for (int i = 0; i < 4; ++i) {
        const int rowb = bm + wr * 64 + i * 16 + quad * 4;
        #pragma unroll
        for (int j = 0; j < 4; ++j) {
            const int col = bn + wc * 64 + j * 16 + l16;
            #pragma unroll
            for (int r = 0; r < 4; ++r) {
                float v = acc[i][j][r] + bvv[j];
                if (flags & 1) v = fmaxf(v, 0.f);
                const size_t idx = (size_t)(rowb + r) * N + col;
                if (flags & 4)      unsafeAtomicAdd(&Cf[idx], v);
                else if (flags & 2) Cf[idx] += v;
                else                Cb[idx] = (__bf16)v;
            }
        }
    }
}

// --------------------------------------------------------------- QKV GEMM (NT), 128x64 tiles
// 768 blocks = exactly 3/CU (R17-proven). z==2 writes s-permuted V^T.
__global__ __launch_bounds__(256) void gemm_qkv(
    const __bf16* __restrict__ A,
    const __bf16* Wa, const __bf16* Wb, const __bf16* Wc,
    const void* ba, const void* bb, const void* bc,
    __bf16* oa, __bf16* ob, __bf16* oc,
    size_t welem_off, size_t belem_off, const int* __restrict__ flagp)
{
    const int f = *flagp;
    const int z = blockIdx.z;
    const __bf16* W = (z == 0) ? Wa : (z == 1) ? Wb : Wc;
    const void* bias = (z == 0) ? ba : (z == 1) ? bb : bc;
    __bf16* Cb = (z == 0) ? oa : (z == 1) ? ob : oc;
    W += welem_off;
    constexpr int K = EE, N = EE;

    __shared__ __bf16 As[2][128 * 64];   // 2 x 16 KB
    __shared__ __bf16 Bs[2][64 * 64];    // 2 x 8 KB   (48 KB total -> 3 blocks/CU)
    const int t = threadIdx.x;
    const int w = t >> 6, lane = t & 63;
    const int quad = lane >> 4, l16 = lane & 15;
    const int bm = blockIdx.x * 128, bn = blockIdx.y * 64;

    v4f acc[2][4] = {};

    #define STAGE_A(dst, kk)                                                    \
        _Pragma("unroll")                                                       \
        for (int ii = 0; ii < 4; ++ii) {                                        \
            const int c  = t + 256 * ii;                                        \
            const int r  = c >> 3, cc = c & 7;                                  \
            const int es = ((cc ^ (r & 7)) * 8);                                \
            gll16(A + (size_t)(bm + r) * K + kk + es, (char*)(dst) + c * 16);   \
        }
    #define STAGE_B(dst, kk)                                                    \
        _Pragma("unroll")                                                       \
        for (int ii = 0; ii < 2; ++ii) {                                        \
            const int c  = t + 256 * ii;                                        \
            const int r  = c >> 3, cc = c & 7;                                  \
            const int es = ((cc ^ (r & 7)) * 8);                                \
            gll16(W + (size_t)(bn + r) * K + kk + es, (char*)(dst) + c * 16);   \
        }

    STAGE_A(As[0], 0)
    STAGE_B(Bs[0], 0)

    int p = 0;
    for (int k0 = 0; k0 < K; k0 += 64) {
        __syncthreads();
        if (k0 + 64 < K) {
            const int kn = k0 + 64, q_ = p ^ 1;
            STAGE_A(As[q_], kn)
            STAGE_B(Bs[q_], kn)
        }
        #pragma unroll
        for (int ks = 0; ks < 2; ++ks) {
            v8bf af[2], bfr[4];
            #pragma unroll
            for (int i = 0; i < 2; ++i) {
                const int row = w * 32 + i * 16 + l16;
                const int ph  = (quad + ks * 4) ^ (row & 7);
                af[i] = *(const v8bf*)&As[p][row * 64 + ph * 8];
            }
            #pragma unroll
            for (int j = 0; j < 4; ++j) {
                const int row = j * 16 + l16;
                const int ph  = (quad + ks * 4) ^ (row & 7);
                bfr[j] = *(const v8bf*)&Bs[p][row * 64 + ph * 8];
            }
            #pragma unroll
            for (int i = 0; i < 2; ++i)
                #pragma unroll
                for (int j = 0; j < 4; ++j)
                    acc[i][j] = __builtin_amdgcn_mfma_f32_16x16x32_bf16(
                        af[i], bfr[j], acc[i][j], 0, 0, 0);
        }
        p ^= 1;
    }
    #undef STAGE_A
    #undef STAGE_B

    float bvv[4];
    #pragma unroll
    for (int j = 0; j < 4; ++j) {
        int col = bn + j * 16 + l16;
        bvv[j] = bias ? ldA(bias, belem_off + col, f) : 0.f;
    }

    if (z == 2) {
        #pragma unroll
        for (int i = 0; i < 2; ++i) {
            const int row0 = bm + w * 32 + i * 16 + quad * 4;  // token (r=0)
            const int b_ = row0 >> 11, sl = row0 & 2047;
            const int s64 = sl & ~63, sloc = sl & 63;
            const int slot = (sloc & 32) + ((sloc >> 2) & 3) * 8 + ((sloc >> 4) & 1) * 4;
            #pragma unroll
            for (int j = 0; j < 4; ++j) {
                const int col = bn + j * 16 + l16;
                const int h_ = col >> 6, d_ = col & 63;
                v4bf u;
                #pragma unroll
                for (int r = 0; r < 4; ++r) u[r] = (__bf16)(acc[i][j][r] + bvv[j]);
                *(v4bf*)(Cb + ((size_t)((b_ * 8 + h_) * 64 + d_)) * SS + s64 + slot) = u;
            }
        }
        return;
    }

    #pragma unroll
    for (int i = 0; i < 2; ++i) {
        const int rowb = bm + w * 32 + i * 16 + quad * 4;
        #pragma unroll
        for (int j = 0; j < 4; ++j) {
            const int col = bn + j * 16 + l16;
            #pragma unroll
            for (int r = 0; r < 4; ++r) {
                const size_t idx = (size_t)(rowb + r) * N + col;
                Cb[idx] = (__bf16)(acc[i][j][r] + bvv[j]);
            }
        }
    }
}

// --------------------------------------------------------------- MFMA attention (AQ=256, 4 waves, 64 q/wave)
// R21: attn is LDS-throughput-bound (per-CU: 8 waves x 16 ds_read_b128/step
// into one 128B/clk LDS unit + 2.1M conflict cycles ~= the 5x over MFMA
// floor; VALU fixes R19/R20 and occupancy R18 confirmed the diagnosis).
// 64 q/wave (4 Q pairs): each kf/vf ds_read_b128 now feeds 4 MFMA; LDS
// fragment reads AND K/V staging per FLOP halve vs 32 q/wave. Block covers
// 256 q -> grid (8,16,2) = 256 blocks = 1/CU; at 1 block/CU occupancy is
// VGPR-irrelevant (~230 VGPR, no spill below 450). Keeps R20's raw v_exp
// + single-barrier K/V double-buffer.
__global__ __launch_bounds__(256) void attn_mfma(
    const __bf16* __restrict__ Qg, const __bf16* __restrict__ Kg,
    const __bf16* __restrict__ Vtg, const int* __restrict__ mask,
    __bf16* __restrict__ Opart, float* __restrict__ MLl)
{
    __shared__ __bf16 Ks[2][64][72];     // [buf][token][d]  (true s order)
    __shared__ __bf16 Vs[2][64][72];     // [buf][d][slot]   (permuted s)
    __shared__ float  mkf[2][64];

    const int t = threadIdx.x;
    const int w = t >> 6, lane = t & 63;      // w in 0..3
    const int quad = lane >> 4, l16 = lane & 15;
    const int bh = blockIdx.y, b = bh >> 3, hh = bh & 7;
    const int q0 = blockIdx.x * 256;
    const int z  = blockIdx.z;
    const int kof = z * KHALF;

    // Q fragments: 4 sub-blocks of 16 q rows each (rows q0 + w*64 + i*16 + l16)
    v8bf qa[4][2];
    #pragma unroll
    for (int i = 0; i < 4; ++i) {
        const __bf16* qr = Qg + ((size_t)(b * SS + q0 + w * 64 + i * 16 + l16)) * EE
                              + hh * DD + quad * 8;
        qa[i][0] = *(const v8bf*)qr;
        qa[i][1] = *(const v8bf*)(qr + 32);
    }

    const int lr = t >> 2, lc = (t & 3) * 16;
    const __bf16* kbase = Kg  + ((size_t)(b * SS + kof + lr)) * EE + hh * DD + lc;
    const __bf16* vbase = Vtg + ((size_t)((b * 8 + hh) * 64 + lr)) * SS + kof + lc;

    // tile 0 -> regs -> buf 0; then prefetch tile 1 into regs
    v8bf ka0 = *(const v8bf*)kbase, ka1 = *(const v8bf*)(kbase + 8);
    v8bf va0 = *(const v8bf*)vbase, va1 = *(const v8bf*)(vbase + 8);
    float mb = 0.f;
    if (t < 64) mb = mask[b * SS + kof + t] ? MBIAS : 0.f;
    *(v8bf*)&Ks[0][lr][lc]     = ka0;
    *(v8bf*)&Ks[0][lr][lc + 8] = ka1;
    *(v8bf*)&Vs[0][lr][lc]     = va0;
    *(v8bf*)&Vs[0][lr][lc + 8] = va1;
    if (t < 64) mkf[0][t] = mb;
    if (64 < KHALF) {
        ka0 = *(const v8bf*)(kbase + (size_t)64 * EE);
        ka1 = *(const v8bf*)(kbase + (size_t)64 * EE + 8);
        va0 = *(const v8bf*)(vbase + 64);
        va1 = *(const v8bf*)(vbase + 64 + 8);
        if (t < 64) mb = mask[b * SS + kof + 64 + t] ? MBIAS : 0.f;
    }
    __syncthreads();

    float lacc[4] = {};
    v4f o[4][4] = {};     // [q-sub][d-tile]

    #pragma unroll 1
    for (int k0 = 0; k0 < KHALF; k0 += 64) {
        const int p = (k0 >> 6) & 1;
        // store tile k0+64 (in regs) to buf p^1; prefetch tile k0+128 to regs.
        if (k0 + 64 < KHALF) {
            *(v8bf*)&Ks[p ^ 1][lr][lc]     = ka0;
            *(v8bf*)&Ks[p ^ 1][lr][lc + 8] = ka1;
            *(v8bf*)&Vs[p ^ 1][lr][lc]     = va0;
            *(v8bf*)&Vs[p ^ 1][lr][lc + 8] = va1;
            if (t < 64) mkf[p ^ 1][t] = mb;
            if (k0 + 128 < KHALF) {
                ka0 = *(const v8bf*)(kbase + (size_t)(k0 + 128) * EE);
                ka1 = *(const v8bf*)(kbase + (size_t)(k0 + 128) * EE + 8);
                va0 = *(const v8bf*)(vbase + (k0 + 128));
                va1 = *(const v8bf*)(vbase + (k0 + 128) + 8);
                if (t < 64) mb = mask[b * SS + kof + k0 + 128 + t] ? MBIAS : 0.f;
            }
        }

        // ---- S^T = K*Q^T : s[i][j] = scores for q-sub i, kv-tile j
        v4f s[4][4];
        __builtin_amdgcn_s_setprio(1);
        #pragma unroll
        for (int j = 0; j < 4; ++j) {
            v8bf kf0 = *(const v8bf*)&Ks[p][j * 16 + l16][quad * 8];
            v8bf kf1 = *(const v8bf*)&Ks[p][j * 16 + l16][32 + quad * 8];
            #pragma unroll
            for (int i = 0; i < 4; ++i) {
                v4f zz = {};
                zz = __builtin_amdgcn_mfma_f32_16x16x32_bf16(kf0, qa[i][0], zz, 0, 0, 0);
                zz = __builtin_amdgcn_mfma_f32_16x16x32_bf16(kf1, qa[i][1], zz, 0, 0, 0);
                s[i][j] = zz;
            }
        }
        __builtin_amdgcn_s_setprio(0);
        float4 mk4[4];
        #pragma unroll
        for (int j = 0; j < 4; ++j) mk4[j] = *(const float4*)&mkf[p][j * 16 + quad * 4];

        // ---- per q-sub: p = exp2(s*scl + bias) via raw v_exp; cvt_pk pack
        v4u plo[4], phi[4];
        #pragma unroll
        for (int i = 0; i < 4; ++i) {
            float e[16];
            float ts = 0.f;
            #pragma unroll
            for (int j = 0; j < 4; ++j) {
                e[j * 4 + 0] = fexp2(fmaf(s[i][j][0], SCL2, mk4[j].x));
                e[j * 4 + 1] = fexp2(fmaf(s[i][j][1], SCL2, mk4[j].y));
                e[j * 4 + 2] = fexp2(fmaf(s[i][j][2], SCL2, mk4[j].z));
                e[j * 4 + 3] = fexp2(fmaf(s[i][j][3], SCL2, mk4[j].w));
                ts += (e[j * 4 + 0] + e[j * 4 + 1]) + (e[j * 4 + 2] + e[j * 4 + 3]);
            }
            lacc[i] += ts;
            #pragma unroll
            for (int d2 = 0; d2 < 4; ++d2) {
                plo[i][d2] = cvtpk(e[d2 * 2],     e[d2 * 2 + 1]);
                phi[i][d2] = cvtpk(e[8 + d2 * 2], e[8 + d2 * 2 + 1]);
            }
        }

        // ---- O^T += V^T * P^T : each vf pair feeds all 4 q-subs
        __builtin_amdgcn_s_setprio(1);
        #pragma unroll
        for (int dt = 0; dt < 4; ++dt) {
            v8bf vf0 = *(const v8bf*)&Vs[p][dt * 16 + l16][quad * 8];
            v8bf vf1 = *(const v8bf*)&Vs[p][dt * 16 + l16][32 + quad * 8];
            #pragma unroll
            for (int i = 0; i < 4; ++i) {
                const v8bf pl = __builtin_bit_cast(v8bf, plo[i]);
                const v8bf ph = __builtin_bit_cast(v8bf, phi[i]);
                o[i][dt] = __builtin_amdgcn_mfma_f32_16x16x32_bf16(vf0, pl, o[i][dt], 0, 0, 0);
                o[i][dt] = __builtin_amdgcn_mfma_f32_16x16x32_bf16(vf1, ph, o[i][dt], 0, 0, 0);
            }
        }
        __builtin_amdgcn_s_setprio(0);
        __syncthreads();   // single barrier per step (R20-proven)
    }

    #pragma unroll
    for (int i = 0; i < 4; ++i) {
        lacc[i] += __shfl_xor(lacc[i], 16, 64);
        lacc[i] += __shfl_xor(lacc[i], 32, 64);
    }

    // ---- epilogue: raw partial O^T per q-sub (col=l16 -> q; row=quad*4+r -> d)
    #pragma unroll
    for (int i = 0; i < 4; ++i) {
        const size_t qi = (size_t)(z * 16 + bh) * SS + (q0 + w * 64 + i * 16 + l16);
        __bf16* op = Opart + qi * 64;
        #pragma unroll
        for (int dt = 0; dt < 4; ++dt) {
            v4bf u;
            #pragma unroll
            for (int r = 0; r < 4; ++r) u[r] = (__bf16)o[i][dt][r];
            *(v4bf*)(op + dt * 16 + quad * 4) = u;
        }
        if (quad == 0) MLl[qi] = lacc[i];
    }
}

// --------------------------------------------------------------- launch
extern "C" void kernel_launch(void* const* d_in, const int* in_sizes, int n_in,
                              void* d_out, int out_size, void* d_ws, size_t ws_size,
                              hipStream_t stream) {
    const void* x_in = d_in[0];
    const int*  mask = (const int*)d_in[1];
    const void* wq = d_in[2];  const void* bq = d_in[3];
    const void* wk = d_in[4];  const void* bk = d_in[5];
    const void* wv = d_in[6];  const void* bv = d_in[7];
    const void* g1 = d_in[8];  const void* b1 = d_in[9];
    const void* g2 = d_in[10]; const void* b2 = d_in[11];
    const void* gf = d_in[12]; const void* bfp= d_in[13];
    const void* W1 = d_in[14]; const void* B1 = d_in[15];
    const void* W2 = d_in[16]; const void* B2 = d_in[17];

    // ws layout (float units), ~49 MB total (ws is 256 MB):
    // X | Qb Kb Vtg Hb | weights | MLl | Opart/MID shared region
    float* base = (float*)d_ws;
    int*   flag = (int*)base;
    float* X   = base + 16;          // NE f32 residual (persistent)
    float* fQ  = X + NE;             // NE/2 floats (Qb)
    float* fK  = fQ + NE / 2;        // NE/2 floats (Kb)
    float* fV  = fK + NE / 2;        // NE/2 floats (Vt global, s-permuted)
    float* fH  = fV + NE / 2;        // NE/2 floats (Hb)
    float* fW  = fH + NE / 2;        // converted weights (contiguous)
    __bf16* Qb    = (__bf16*)fQ;
    __bf16* Kb    = (__bf16*)fK;
    __bf16* Vtg   = (__bf16*)fV;     // [ (b*8+h)*64 + d ][ s (permuted/64) ]
    __bf16* Hb    = (__bf16*)fH;
    __bf16* wqc = (__bf16*)fW;
    __bf16* wkc = wqc + 2 * EE * EE;
    __bf16* wvc = wkc + 2 * EE * EE;
    __bf16* W1c = wvc + 2 * EE * EE;
    __bf16* W2c = W1c + DFF_ * EE;
    float* MLl = (float*)(W2c + (size_t)EE * DFF_);   // KSPLIT*16*SS f32
    float* fO  = MLl + (size_t)KSPLIT * 16 * SS;
    __bf16* Opart = (__bf16*)fO;     // KSPLIT x 16 bh x 2048 x 64 bf16
    __bf16* MID   = (__bf16*)fO;     // NTOK*DFF bf16 (aliases dead Opart)

    // x -> X (f32) fused with layer-0 LN1 -> Hb; self-sniffs dtype
    cvt_ln<<<NTOK, 256, 0, stream>>>(x_in, X, g1, b1, Hb, flag);
    wcvt_all<<<1792, 256, 0, stream>>>(wq, wk, wv, W1, W2, wqc, flag);

    const dim3 gQKV(NTOK / 128, EE / 64, 3);       // 768 blocks = 3/CU exact
    const dim3 gF1 (NTOK / 128, DFF_ / 128, 1);    // 512 blocks
    const dim3 gF2 (NTOK / 128, EE / 128, 4);      // 512 blocks (split-K x4)
    const dim3 gAtt(SS / 256, BB * HH, KSPLIT);    // 256 blocks = 1/CU, 64 q/wave

    for (int l = 0; l < 2; ++l) {
        const size_t wo = (size_t)l * EE * EE, bo = (size_t)l * EE;
        if (l > 0)
            ln_kernel<<<NTOK, 256, 0, stream>>>(X, g1, b1, Hb, nullptr, flag);
        gemm_qkv<<<gQKV, 256, 0, stream>>>(Hb, wqc, wkc, wvc, bq, bk, bv,
            Qb, Kb, Vtg, wo, bo, flag);
        attn_mfma<<<gAtt, 256, 0, stream>>>(Qb, Kb, Vtg, mask, Opart, MLl);
        combine_ln<<<NTOK, 256, 0, stream>>>(Opart, MLl, g2, b2, X, Hb, flag);
        gemm_mfma<<<gF1, 256, 0, stream>>>(Hb, W1c, W1c, W1c, B1, B1, B1,
            MID, MID, MID, nullptr, NTOK, DFF_, EE, 1, 0, 0, flag);
        gemm_mfma<<<gF2, 256, 0, stream>>>(MID, W2c, W2c, W2c, B2, B2, B2,
            nullptr, nullptr, nullptr, X, NTOK, EE, DFF_, 2 | 4, 0, 0, flag);
    }
    ln_kernel<<<NTOK, 256, 0, stream>>>(X, gf, bfp, nullptr, d_out, flag);
}

// Round 9
// 339.575 us; speedup vs baseline: 1.0436x; 1.0436x over previous
//
#include <hip/hip_runtime.h>
#include <hip/hip_bf16.h>

// Problem constants (B,S,E,H,L,DFF) = (2,2048,512,8,2,2048), D=64
constexpr int BB   = 2;
constexpr int SS   = 2048;
constexpr int EE   = 512;
constexpr int HH   = 8;
constexpr int DD   = 64;
constexpr int DFF_ = 2048;
constexpr int NTOK = BB * SS;          // 4096 tokens
constexpr int NE   = NTOK * EE;        // 2097152
constexpr float EPSF  = 1e-5f;
constexpr float SCL2  = 0.125f * 1.44269504088896f;  // 1/sqrt(D) * log2(e)
constexpr float MBIAS = -1e30f;
constexpr int KSPLIT = 2;              // attention split-K parts (R3-proven)
constexpr int KHALF  = SS / KSPLIT;    // 1024 kv per block

typedef __bf16 v8bf __attribute__((ext_vector_type(8)));
typedef __bf16 v4bf __attribute__((ext_vector_type(4)));
typedef float  v4f  __attribute__((ext_vector_type(4)));
typedef unsigned int v4u __attribute__((ext_vector_type(4)));

__device__ __forceinline__ float bf2f(unsigned short u) {
    return __uint_as_float(((unsigned int)u) << 16);
}
__device__ __forceinline__ float bf2f(__bf16 u) {
    unsigned short us = __builtin_bit_cast(unsigned short, u);
    return __uint_as_float(((unsigned int)us) << 16);
}
// adaptive load: f=1 -> float32 buffer, f=0 -> bf16 buffer
__device__ __forceinline__ float ldA(const void* p, size_t i, int f) {
    return f ? ((const float*)p)[i] : bf2f(((const unsigned short*)p)[i]);
}
// async global->LDS, 16 B per lane (m97-verified path)
__device__ __forceinline__ void gll16(const void* g, void* l) {
    __builtin_amdgcn_global_load_lds(
        (const __attribute__((address_space(1))) void*)g,
        (__attribute__((address_space(3))) void*)l, 16, 0, 0);
}
// pack 2 f32 -> 1 dword of 2 bf16 (lo=a, hi=b) in ONE instruction.
__device__ __forceinline__ unsigned cvtpk(float a, float b) {
    unsigned r;
    asm("v_cvt_pk_bf16_f32 %0, %1, %2" : "=v"(r) : "v"(a), "v"(b));
    return r;
}
// R20: raw v_exp_f32. Without -ffast-math, exp2f lowers to the OCML
// precision path (~5-10 VALU of range fixup per call) — the hidden 4x VALU
// multiplier behind attn's measured VALUBusy=41%. Raw instruction is exact
// enough here (masked lanes: v_exp(-1e30)=0; scores are small).
__device__ __forceinline__ float fexp2(float x) {
#if __has_builtin(__builtin_amdgcn_exp2f)
    return __builtin_amdgcn_exp2f(x);
#else
    return exp2f(x);
#endif
}

// --------------------------------------------------------------- cvt x -> f32 fused with layer-0 LN1
// Self-sniffing (R17): each block decides dtype locally; block 0 publishes
// the flag for all later (stream-ordered) dispatches.
__global__ __launch_bounds__(256) void cvt_ln(
    const void* __restrict__ in, float* __restrict__ X,
    const void* __restrict__ g, const void* __restrict__ b,
    __bf16* __restrict__ Hb, int* __restrict__ flagw)
{
    const int row = blockIdx.x, t = threadIdx.x;
    __shared__ float red[8], st[2];
    __shared__ int scnt[4], sflag;
    {
        const unsigned short* u = (const unsigned short*)in;
        int bad = 0;
        #pragma unroll
        for (int i = 0; i < 2; ++i) {
            float v = bf2f(u[t + 256 * i]);
            if (!(fabsf(v) < 1000.f)) bad++;
        }
        #pragma unroll
        for (int off = 32; off > 0; off >>= 1) bad += __shfl_down(bad, off, 64);
        if ((t & 63) == 0) scnt[t >> 6] = bad;
        __syncthreads();
        if (t == 0) sflag = (scnt[0] + scnt[1] + scnt[2] + scnt[3] > 1) ? 1 : 0;
        __syncthreads();
    }
    const int f = sflag;
    if (row == 0 && t == 0) *flagw = f;

    const size_t i0 = (size_t)row * EE + t, i1 = i0 + 256;
    float v0 = ldA(in, i0, f);
    float v1 = ldA(in, i1, f);
    float s = v0 + v1, q = v0 * v0 + v1 * v1;
    #pragma unroll
    for (int off = 32; off > 0; off >>= 1) {
        s += __shfl_down(s, off, 64);
        q += __shfl_down(q, off, 64);
    }
    const int wid = t >> 6;
    if ((t & 63) == 0) { red[wid] = s; red[4 + wid] = q; }
    __syncthreads();
    if (t == 0) {
        float S_ = red[0] + red[1] + red[2] + red[3];
        float Q_ = red[4] + red[5] + red[6] + red[7];
        float mu = S_ / EE;
        st[0] = mu;
        st[1] = rsqrtf(Q_ / EE - mu * mu + EPSF);
    }
    __syncthreads();
    const float mu = st[0], rs = st[1];
    float o0 = (v0 - mu) * rs * ldA(g, t, f)       + ldA(b, t, f);
    float o1 = (v1 - mu) * rs * ldA(g, t + 256, f) + ldA(b, t + 256, f);
    X[i0] = v0; X[i1] = v1;
    Hb[i0] = (__bf16)o0; Hb[i1] = (__bf16)o1;
}

// --------------------------------------------------------------- all weights -> bf16 (one launch)
__global__ void wcvt_all(const void* __restrict__ wq, const void* __restrict__ wk,
                         const void* __restrict__ wv, const void* __restrict__ W1,
                         const void* __restrict__ W2, __bf16* __restrict__ out,
                         const int* __restrict__ flagp) {
    const int f = *flagp;
    const int i = (blockIdx.x * blockDim.x + threadIdx.x) * 8;
    constexpr int n1 = 2 * EE * EE;      // 524288 per QKV tensor
    constexpr int nf = DFF_ * EE;        // 1048576 per FFN tensor
    const void* src; int off;
    if      (i < n1)          { src = wq; off = i; }
    else if (i < 2 * n1)      { src = wk; off = i - n1; }
    else if (i < 3 * n1)      { src = wv; off = i - 2 * n1; }
    else if (i < 3 * n1 + nf) { src = W1; off = i - 3 * n1; }
    else                      { src = W2; off = i - 3 * n1 - nf; }
    if (f) {
        const float* p = (const float*)src + off;
        #pragma unroll
        for (int j = 0; j < 8; ++j) out[i + j] = (__bf16)p[j];
    } else {
        *(uint4*)(out + i) = *(const uint4*)((const unsigned short*)src + off);
    }
}

// --------------------------------------------------------------- layernorm (single)
__global__ __launch_bounds__(256) void ln_kernel(
    const float* __restrict__ src,
    const void* __restrict__ g, const void* __restrict__ b,
    __bf16* __restrict__ dstb, void* __restrict__ outp,
    const int* __restrict__ flagp)
{
    const int f = *flagp;
    const int row = blockIdx.x, t = threadIdx.x;
    const float* x = src + (size_t)row * EE;
    float v0 = x[t], v1 = x[t + 256];
    float s = v0 + v1, q = v0 * v0 + v1 * v1;
    #pragma unroll
    for (int off = 32; off > 0; off >>= 1) {
        s += __shfl_down(s, off, 64);
        q += __shfl_down(q, off, 64);
    }
    __shared__ float red[8], st[2];
    const int wid = t >> 6;
    if ((t & 63) == 0) { red[wid] = s; red[4 + wid] = q; }
    __syncthreads();
    if (t == 0) {
        float S_ = red[0] + red[1] + red[2] + red[3];
        float Q_ = red[4] + red[5] + red[6] + red[7];
        float mu = S_ / EE;
        st[0] = mu;
        st[1] = rsqrtf(Q_ / EE - mu * mu + EPSF);
    }
    __syncthreads();
    const float mu = st[0], rs = st[1];
    float o0 = (v0 - mu) * rs, o1 = (v1 - mu) * rs;
    if (g) {
        o0 = o0 * ldA(g, t, f)       + ldA(b, t, f);
        o1 = o1 * ldA(g, t + 256, f) + ldA(b, t + 256, f);
    }
    const size_t i0 = (size_t)row * EE + t, i1 = i0 + 256;
    if (dstb) { dstb[i0] = (__bf16)o0; dstb[i1] = (__bf16)o1; }
    if (outp) {
        if (f) { ((float*)outp)[i0] = o0; ((float*)outp)[i1] = o1; }
        else {
            ((__hip_bfloat16*)outp)[i0] = __float2bfloat16(o0);
            ((__hip_bfloat16*)outp)[i1] = __float2bfloat16(o1);
        }
    }
}

// --------------------------------------------------------------- combine + residual + double LN
__global__ __launch_bounds__(256) void combine_ln(
    const __bf16* __restrict__ Opart, const float* __restrict__ MLl,
    const void* __restrict__ g2, const void* __restrict__ b2,
    float* __restrict__ X, __bf16* __restrict__ Hb,
    const int* __restrict__ flagp)
{
    const int f = *flagp;
    const int tok = blockIdx.x, t = threadIdx.x;
    const int b = tok >> 11, s_ = tok & 2047;
    __shared__ float cinv[8];
    __shared__ float red[8], st[2];
    if (t < 8) {
        float l = 0.f;
        #pragma unroll
        for (int zz = 0; zz < KSPLIT; ++zz)
            l += MLl[(size_t)(zz * 16 + b * 8 + t) * SS + s_];
        cinv[t] = (l > 0.f) ? 1.f / l : 0.f;
    }
    __syncthreads();
    float a0 = 0.f, a1 = 0.f;
    {
        int c = t, h = c >> 6, d = c & 63;
        #pragma unroll
        for (int zz = 0; zz < KSPLIT; ++zz)
            a0 += bf2f(Opart[((size_t)(zz * 16 + b * 8 + h) * SS + s_) * 64 + d]);
        a0 *= cinv[h];
        c = t + 256; h = c >> 6; d = c & 63;
        #pragma unroll
        for (int zz = 0; zz < KSPLIT; ++zz)
            a1 += bf2f(Opart[((size_t)(zz * 16 + b * 8 + h) * SS + s_) * 64 + d]);
        a1 *= cinv[h];
    }
    const int wid = t >> 6;
    {
        float s = a0 + a1, q = a0 * a0 + a1 * a1;
        #pragma unroll
        for (int off = 32; off > 0; off >>= 1) {
            s += __shfl_down(s, off, 64);
            q += __shfl_down(q, off, 64);
        }
        if ((t & 63) == 0) { red[wid] = s; red[4 + wid] = q; }
    }
    __syncthreads();
    if (t == 0) {
        float S_ = red[0] + red[1] + red[2] + red[3];
        float Q_ = red[4] + red[5] + red[6] + red[7];
        float mu = S_ / EE;
        st[0] = mu;
        st[1] = rsqrtf(Q_ / EE - mu * mu + EPSF);
    }
    __syncthreads();
    const float mu1 = st[0], rs1 = st[1];
    const size_t i0 = (size_t)tok * EE + t, i1 = i0 + 256;
    float l0v = (a0 - mu1) * rs1 * ldA(g2, t, f)       + ldA(b2, t, f);
    float l1v = (a1 - mu1) * rs1 * ldA(g2, t + 256, f) + ldA(b2, t + 256, f);
    float x0 = X[i0] + l0v, x1 = X[i1] + l1v;
    __syncthreads();
    {
        float s = x0 + x1, q = x0 * x0 + x1 * x1;
        #pragma unroll
        for (int off = 32; off > 0; off >>= 1) {
            s += __shfl_down(s, off, 64);
            q += __shfl_down(q, off, 64);
        }
        if ((t & 63) == 0) { red[wid] = s; red[4 + wid] = q; }
    }
    __syncthreads();
    if (t == 0) {
        float S_ = red[0] + red[1] + red[2] + red[3];
        float Q_ = red[4] + red[5] + red[6] + red[7];
        float mu = S_ / EE;
        st[0] = mu;
        st[1] = rsqrtf(Q_ / EE - mu * mu + EPSF);
    }
    __syncthreads();
    const float mu2 = st[0], rs2 = st[1];
    X[i0] = x0; X[i1] = x1;
    Hb[i0] = (__bf16)((x0 - mu2) * rs2);
    Hb[i1] = (__bf16)((x1 - mu2) * rs2);
}

// --------------------------------------------------------------- MFMA GEMM (NT), 128x128, double-buffered
// BK=64 + both-sides XOR swizzle (R16). Used by FFN1/FFN2 (exact 2 blocks/CU).
__global__ __launch_bounds__(256) void gemm_mfma(
    const __bf16* __restrict__ A,
    const __bf16* Wa, const __bf16* Wb, const __bf16* Wc,
    const void* ba, const void* bb, const void* bc,
    __bf16* oa, __bf16* ob, __bf16* oc,
    float* __restrict__ Cf,
    int M, int N, int K, int flags,
    size_t welem_off, size_t belem_off, const int* __restrict__ flagp)
{
    const int f = *flagp;
    const int z = blockIdx.z;
    const __bf16* W = (z == 0) ? Wa : (z == 1) ? Wb : Wc;
    const void* bias = (z == 0) ? ba : (z == 1) ? bb : bc;
    __bf16* Cb = (z == 0) ? oa : (z == 1) ? ob : oc;
    W += welem_off;
    int kbeg = 0, kend = K;
    if (flags & 4) {
        const int ks = K >> 2;
        kbeg = z * ks; kend = kbeg + ks;
        if (z != 0) bias = nullptr;
    }

    __shared__ __bf16 As[2][128 * 64];   // 2 x 16 KB
    __shared__ __bf16 Bs[2][128 * 64];   // 2 x 16 KB  (64 KB total -> 2 blocks/CU)
    const int t = threadIdx.x;
    const int w = t >> 6, lane = t & 63;
    const int quad = lane >> 4, l16 = lane & 15;
    const int wr = w >> 1, wc = w & 1;
    const int bm = blockIdx.x * 128, bn = blockIdx.y * 128;

    v4f acc[4][4] = {};

    #define STAGE_TILE(dst, src, rowbase, kk)                                   \
        _Pragma("unroll")                                                       \
        for (int ii = 0; ii < 4; ++ii) {                                        \
            const int c  = t + 256 * ii;                                        \
            const int r  = c >> 3, cc = c & 7;                                  \
            const int es = ((cc ^ (r & 7)) * 8);                                \
            gll16(src + (size_t)(rowbase + r) * K + kk + es,                    \
                  (char*)(dst) + c * 16);                                       \
        }

    STAGE_TILE(As[0], A, bm, kbeg)
    STAGE_TILE(Bs[0], W, bn, kbeg)

    int p = 0;
    for (int k0 = kbeg; k0 < kend; k0 += 64) {
        __syncthreads();
        if (k0 + 64 < kend) {
            const int kn = k0 + 64, q_ = p ^ 1;
            STAGE_TILE(As[q_], A, bm, kn)
            STAGE_TILE(Bs[q_], W, bn, kn)
        }
        #pragma unroll
        for (int ks = 0; ks < 2; ++ks) {
            v8bf af[4], bfr[4];
            #pragma unroll
            for (int i = 0; i < 4; ++i) {
                const int row = wr * 64 + i * 16 + l16;
                const int ph  = (quad + ks * 4) ^ (row & 7);
                af[i] = *(const v8bf*)&As[p][row * 64 + ph * 8];
            }
            #pragma unroll
            for (int j = 0; j < 4; ++j) {
                const int row = wc * 64 + j * 16 + l16;
                const int ph  = (quad + ks * 4) ^ (row & 7);
                bfr[j] = *(const v8bf*)&Bs[p][row * 64 + ph * 8];
            }
            #pragma unroll
            for (int i = 0; i < 4; ++i)
                #pragma unroll
                for (int j = 0; j < 4; ++j)
                    acc[i][j] = __builtin_amdgcn_mfma_f32_16x16x32_bf16(
                        af[i], bfr[j], acc[i][j], 0, 0, 0);
        }
        p ^= 1;
    }
    #undef STAGE_TILE

    float bvv[4];
    #pragma unroll
    for (int j = 0; j < 4; ++j) {
        int col = bn + wc * 64 + j * 16 + l16;
        bvv[j] = bias ? ldA(bias, belem_off + col, f) : 0.f;
    }

    #pragma unroll
    for (int i = 0; i < 4; ++i) {
        const int rowb = bm + wr * 64 + i * 16 + quad * 4;
        #pragma unroll
        for (int j = 0; j < 4; ++j) {
            const int col = bn + wc * 64 + j * 16 + l16;
            #pragma unroll
            for (int r = 0; r < 4; ++r) {
                float v = acc[i][j][r] + bvv[j];
                if (flags & 1) v = fmaxf(v, 0.f);
                const size_t idx = (size_t)(rowb + r) * N + col;
                if (flags & 4)      unsafeAtomicAdd(&Cf[idx], v);
                else if (flags & 2) Cf[idx] += v;
                else                Cb[idx] = (__bf16)v;
            }
        }
    }
}

// --------------------------------------------------------------- QKV GEMM (NT), 128x64 tiles
// 768 blocks = exactly 3/CU (R17-proven). z==2 writes s-permuted V^T.
__global__ __launch_bounds__(256) void gemm_qkv(
    const __bf16* __restrict__ A,
    const __bf16* Wa, const __bf16* Wb, const __bf16* Wc,
    const void* ba, const void* bb, const void* bc,
    __bf16* oa, __bf16* ob, __bf16* oc,
    size_t welem_off, size_t belem_off, const int* __restrict__ flagp)
{
    const int f = *flagp;
    const int z = blockIdx.z;
    const __bf16* W = (z == 0) ? Wa : (z == 1) ? Wb : Wc;
    const void* bias = (z == 0) ? ba : (z == 1) ? bb : bc;
    __bf16* Cb = (z == 0) ? oa : (z == 1) ? ob : oc;
    W += welem_off;
    constexpr int K = EE, N = EE;

    __shared__ __bf16 As[2][128 * 64];   // 2 x 16 KB
    __shared__ __bf16 Bs[2][64 * 64];    // 2 x 8 KB   (48 KB total -> 3 blocks/CU)
    const int t = threadIdx.x;
    const int w = t >> 6, lane = t & 63;
    const int quad = lane >> 4, l16 = lane & 15;
    const int bm = blockIdx.x * 128, bn = blockIdx.y * 64;

    v4f acc[2][4] = {};

    #define STAGE_A(dst, kk)                                                    \
        _Pragma("unroll")                                                       \
        for (int ii = 0; ii < 4; ++ii) {                                        \
            const int c  = t + 256 * ii;                                        \
            const int r  = c >> 3, cc = c & 7;                                  \
            const int es = ((cc ^ (r & 7)) * 8);                                \
            gll16(A + (size_t)(bm + r) * K + kk + es, (char*)(dst) + c * 16);   \
        }
    #define STAGE_B(dst, kk)                                                    \
        _Pragma("unroll")                                                       \
        for (int ii = 0; ii < 2; ++ii) {                                        \
            const int c  = t + 256 * ii;                                        \
            const int r  = c >> 3, cc = c & 7;                                  \
            const int es = ((cc ^ (r & 7)) * 8);                                \
            gll16(W + (size_t)(bn + r) * K + kk + es, (char*)(dst) + c * 16);   \
        }

    STAGE_A(As[0], 0)
    STAGE_B(Bs[0], 0)

    int p = 0;
    for (int k0 = 0; k0 < K; k0 += 64) {
        __syncthreads();
        if (k0 + 64 < K) {
            const int kn = k0 + 64, q_ = p ^ 1;
            STAGE_A(As[q_], kn)
            STAGE_B(Bs[q_], kn)
        }
        #pragma unroll
        for (int ks = 0; ks < 2; ++ks) {
            v8bf af[2], bfr[4];
            #pragma unroll
            for (int i = 0; i < 2; ++i) {
                const int row = w * 32 + i * 16 + l16;
                const int ph  = (quad + ks * 4) ^ (row & 7);
                af[i] = *(const v8bf*)&As[p][row * 64 + ph * 8];
            }
            #pragma unroll
            for (int j = 0; j < 4; ++j) {
                const int row = j * 16 + l16;
                const int ph  = (quad + ks * 4) ^ (row & 7);
                bfr[j] = *(const v8bf*)&Bs[p][row * 64 + ph * 8];
            }
            #pragma unroll
            for (int i = 0; i < 2; ++i)
                #pragma unroll
                for (int j = 0; j < 4; ++j)
                    acc[i][j] = __builtin_amdgcn_mfma_f32_16x16x32_bf16(
                        af[i], bfr[j], acc[i][j], 0, 0, 0);
        }
        p ^= 1;
    }
    #undef STAGE_A
    #undef STAGE_B

    float bvv[4];
    #pragma unroll
    for (int j = 0; j < 4; ++j) {
        int col = bn + j * 16 + l16;
        bvv[j] = bias ? ldA(bias, belem_off + col, f) : 0.f;
    }

    if (z == 2) {
        #pragma unroll
        for (int i = 0; i < 2; ++i) {
            const int row0 = bm + w * 32 + i * 16 + quad * 4;  // token (r=0)
            const int b_ = row0 >> 11, sl = row0 & 2047;
            const int s64 = sl & ~63, sloc = sl & 63;
            const int slot = (sloc & 32) + ((sloc >> 2) & 3) * 8 + ((sloc >> 4) & 1) * 4;
            #pragma unroll
            for (int j = 0; j < 4; ++j) {
                const int col = bn + j * 16 + l16;
                const int h_ = col >> 6, d_ = col & 63;
                v4bf u;
                #pragma unroll
                for (int r = 0; r < 4; ++r) u[r] = (__bf16)(acc[i][j][r] + bvv[j]);
                *(v4bf*)(Cb + ((size_t)((b_ * 8 + h_) * 64 + d_)) * SS + s64 + slot) = u;
            }
        }
        return;
    }

    #pragma unroll
    for (int i = 0; i < 2; ++i) {
        const int rowb = bm + w * 32 + i * 16 + quad * 4;
        #pragma unroll
        for (int j = 0; j < 4; ++j) {
            const int col = bn + j * 16 + l16;
            #pragma unroll
            for (int r = 0; r < 4; ++r) {
                const size_t idx = (size_t)(rowb + r) * N + col;
                Cb[idx] = (__bf16)(acc[i][j][r] + bvv[j]);
            }
        }
    }
}

// --------------------------------------------------------------- MFMA attention (AQ=128, 4 waves, 32 q/wave)
// R22 = R6 exact revert (best measured: 339.9us). Session ledger: 2 blocks/CU
// + 32 q/wave + raw v_exp + single-barrier dbuf is a measured local optimum;
// both neighbors (4 blocks/CU R18, 64 q/wave @ 1 block/CU R21) regressed.
__global__ __launch_bounds__(256) void attn_mfma(
    const __bf16* __restrict__ Qg, const __bf16* __restrict__ Kg,
    const __bf16* __restrict__ Vtg, const int* __restrict__ mask,
    __bf16* __restrict__ Opart, float* __restrict__ MLl)
{
    __shared__ __bf16 Ks[2][64][72];     // [buf][token][d]  (true s order)
    __shared__ __bf16 Vs[2][64][72];     // [buf][d][slot]   (permuted s)
    __shared__ float  mkf[2][64];

    const int t = threadIdx.x;
    const int w = t >> 6, lane = t & 63;      // w in 0..3
    const int quad = lane >> 4, l16 = lane & 15;
    const int bh = blockIdx.y, b = bh >> 3, hh = bh & 7;
    const int q0 = blockIdx.x * 128;
    const int z  = blockIdx.z;
    const int kof = z * KHALF;

    const __bf16* qrow0 = Qg + ((size_t)(b * SS + q0 + w * 32 + l16)) * EE + hh * DD + quad * 8;
    const __bf16* qrow1 = qrow0 + (size_t)16 * EE;
    const v8bf qa00 = *(const v8bf*)qrow0;
    const v8bf qa01 = *(const v8bf*)(qrow0 + 32);
    const v8bf qa10 = *(const v8bf*)qrow1;
    const v8bf qa11 = *(const v8bf*)(qrow1 + 32);

    const int lr = t >> 2, lc = (t & 3) * 16;
    const __bf16* kbase = Kg  + ((size_t)(b * SS + kof + lr)) * EE + hh * DD + lc;
    const __bf16* vbase = Vtg + ((size_t)((b * 8 + hh) * 64 + lr)) * SS + kof + lc;

    // tile 0 -> regs -> buf 0; then prefetch tile 1 into regs
    v8bf ka0 = *(const v8bf*)kbase, ka1 = *(const v8bf*)(kbase + 8);
    v8bf va0 = *(const v8bf*)vbase, va1 = *(const v8bf*)(vbase + 8);
    float mb = 0.f;
    if (t < 64) mb = mask[b * SS + kof + t] ? MBIAS : 0.f;
    *(v8bf*)&Ks[0][lr][lc]     = ka0;
    *(v8bf*)&Ks[0][lr][lc + 8] = ka1;
    *(v8bf*)&Vs[0][lr][lc]     = va0;
    *(v8bf*)&Vs[0][lr][lc + 8] = va1;
    if (t < 64) mkf[0][t] = mb;
    if (64 < KHALF) {
        ka0 = *(const v8bf*)(kbase + (size_t)64 * EE);
        ka1 = *(const v8bf*)(kbase + (size_t)64 * EE + 8);
        va0 = *(const v8bf*)(vbase + 64);
        va1 = *(const v8bf*)(vbase + 64 + 8);
        if (t < 64) mb = mask[b * SS + kof + 64 + t] ? MBIAS : 0.f;
    }
    __syncthreads();

    float l0 = 0.f, l1 = 0.f;
    v4f o0[4] = {}, o1[4] = {};

    #pragma unroll 1
    for (int k0 = 0; k0 < KHALF; k0 += 64) {
        const int p = (k0 >> 6) & 1;
        // store tile k0+64 (in regs) to buf p^1; prefetch tile k0+128 to regs.
        // Safe: all waves finished reading buf p^1 (tile k0-64) at the
        // barrier that ended the previous iteration.
        if (k0 + 64 < KHALF) {
            *(v8bf*)&Ks[p ^ 1][lr][lc]     = ka0;
            *(v8bf*)&Ks[p ^ 1][lr][lc + 8] = ka1;
            *(v8bf*)&Vs[p ^ 1][lr][lc]     = va0;
            *(v8bf*)&Vs[p ^ 1][lr][lc + 8] = va1;
            if (t < 64) mkf[p ^ 1][t] = mb;
            if (k0 + 128 < KHALF) {
                ka0 = *(const v8bf*)(kbase + (size_t)(k0 + 128) * EE);
                ka1 = *(const v8bf*)(kbase + (size_t)(k0 + 128) * EE + 8);
                va0 = *(const v8bf*)(vbase + (k0 + 128));
                va1 = *(const v8bf*)(vbase + (k0 + 128) + 8);
                if (t < 64) mb = mask[b * SS + kof + k0 + 128 + t] ? MBIAS : 0.f;
            }
        }

        v4f s0[4], s1[4];
        __builtin_amdgcn_s_setprio(1);
        #pragma unroll
        for (int j = 0; j < 4; ++j) {
            v8bf kf0 = *(const v8bf*)&Ks[p][j * 16 + l16][quad * 8];
            v8bf kf1 = *(const v8bf*)&Ks[p][j * 16 + l16][32 + quad * 8];
            v4f za = {}, zb = {};
            za = __builtin_amdgcn_mfma_f32_16x16x32_bf16(kf0, qa00, za, 0, 0, 0);
            za = __builtin_amdgcn_mfma_f32_16x16x32_bf16(kf1, qa01, za, 0, 0, 0);
            zb = __builtin_amdgcn_mfma_f32_16x16x32_bf16(kf0, qa10, zb, 0, 0, 0);
            zb = __builtin_amdgcn_mfma_f32_16x16x32_bf16(kf1, qa11, zb, 0, 0, 0);
            s0[j] = za; s1[j] = zb;
        }
        __builtin_amdgcn_s_setprio(0);
        float4 mk4[4];
        #pragma unroll
        for (int j = 0; j < 4; ++j) mk4[j] = *(const float4*)&mkf[p][j * 16 + quad * 4];

        // p = exp2(s*scl + maskbias) via raw v_exp_f32; cvt_pk packing.
        float ea[16], eb[16];
        float t0 = 0.f, t1 = 0.f;
        #pragma unroll
        for (int j = 0; j < 4; ++j) {
            ea[j * 4 + 0] = fexp2(fmaf(s0[j][0], SCL2, mk4[j].x));
            ea[j * 4 + 1] = fexp2(fmaf(s0[j][1], SCL2, mk4[j].y));
            ea[j * 4 + 2] = fexp2(fmaf(s0[j][2], SCL2, mk4[j].z));
            ea[j * 4 + 3] = fexp2(fmaf(s0[j][3], SCL2, mk4[j].w));
            eb[j * 4 + 0] = fexp2(fmaf(s1[j][0], SCL2, mk4[j].x));
            eb[j * 4 + 1] = fexp2(fmaf(s1[j][1], SCL2, mk4[j].y));
            eb[j * 4 + 2] = fexp2(fmaf(s1[j][2], SCL2, mk4[j].z));
            eb[j * 4 + 3] = fexp2(fmaf(s1[j][3], SCL2, mk4[j].w));
            t0 += (ea[j * 4 + 0] + ea[j * 4 + 1]) + (ea[j * 4 + 2] + ea[j * 4 + 3]);
            t1 += (eb[j * 4 + 0] + eb[j * 4 + 1]) + (eb[j * 4 + 2] + eb[j * 4 + 3]);
        }
        l0 += t0; l1 += t1;

        v4u ua0, ua1, ub0, ub1;
        #pragma unroll
        for (int d2 = 0; d2 < 4; ++d2) {
            ua0[d2] = cvtpk(ea[d2 * 2],     ea[d2 * 2 + 1]);
            ua1[d2] = cvtpk(ea[8 + d2 * 2], ea[8 + d2 * 2 + 1]);
            ub0[d2] = cvtpk(eb[d2 * 2],     eb[d2 * 2 + 1]);
            ub1[d2] = cvtpk(eb[8 + d2 * 2], eb[8 + d2 * 2 + 1]);
        }
        const v8bf p00 = __builtin_bit_cast(v8bf, ua0);
        const v8bf p01 = __builtin_bit_cast(v8bf, ua1);
        const v8bf p10 = __builtin_bit_cast(v8bf, ub0);
        const v8bf p11 = __builtin_bit_cast(v8bf, ub1);

        __builtin_amdgcn_s_setprio(1);
        #pragma unroll
        for (int dt = 0; dt < 4; ++dt) {
            v8bf vf0 = *(const v8bf*)&Vs[p][dt * 16 + l16][quad * 8];
            v8bf vf1 = *(const v8bf*)&Vs[p][dt * 16 + l16][32 + quad * 8];
            o0[dt] = __builtin_amdgcn_mfma_f32_16x16x32_bf16(vf0, p00, o0[dt], 0, 0, 0);
            o0[dt] = __builtin_amdgcn_mfma_f32_16x16x32_bf16(vf1, p01, o0[dt], 0, 0, 0);
            o1[dt] = __builtin_amdgcn_mfma_f32_16x16x32_bf16(vf0, p10, o1[dt], 0, 0, 0);
            o1[dt] = __builtin_amdgcn_mfma_f32_16x16x32_bf16(vf1, p11, o1[dt], 0, 0, 0);
        }
        __builtin_amdgcn_s_setprio(0);
        __syncthreads();   // single barrier per step: stores to p^1 visible,
                           // reads of p done before it becomes a store target
    }

    l0 += __shfl_xor(l0, 16, 64);
    l0 += __shfl_xor(l0, 32, 64);
    l1 += __shfl_xor(l1, 16, 64);
    l1 += __shfl_xor(l1, 32, 64);

    const size_t qi0 = (size_t)(z * 16 + bh) * SS + (q0 + w * 32 + l16);
    const size_t qi1 = qi0 + 16;
    __bf16* op0 = Opart + qi0 * 64;
    __bf16* op1 = Opart + qi1 * 64;
    #pragma unroll
    for (int dt = 0; dt < 4; ++dt) {
        v4bf u0, u1;
        #pragma unroll
        for (int r = 0; r < 4; ++r) { u0[r] = (__bf16)o0[dt][r]; u1[r] = (__bf16)o1[dt][r]; }
        *(v4bf*)(op0 + dt * 16 + quad * 4) = u0;
        *(v4bf*)(op1 + dt * 16 + quad * 4) = u1;
    }
    if (quad == 0) { MLl[qi0] = l0; MLl[qi1] = l1; }
}

// --------------------------------------------------------------- launch
extern "C" void kernel_launch(void* const* d_in, const int* in_sizes, int n_in,
                              void* d_out, int out_size, void* d_ws, size_t ws_size,
                              hipStream_t stream) {
    const void* x_in = d_in[0];
    const int*  mask = (const int*)d_in[1];
    const void* wq = d_in[2];  const void* bq = d_in[3];
    const void* wk = d_in[4];  const void* bk = d_in[5];
    const void* wv = d_in[6];  const void* bv = d_in[7];
    const void* g1 = d_in[8];  const void* b1 = d_in[9];
    const void* g2 = d_in[10]; const void* b2 = d_in[11];
    const void* gf = d_in[12]; const void* bfp= d_in[13];
    const void* W1 = d_in[14]; const void* B1 = d_in[15];
    const void* W2 = d_in[16]; const void* B2 = d_in[17];

    // ws layout (float units), ~49 MB total (ws is 256 MB):
    // X | Qb Kb Vtg Hb | weights | MLl | Opart/MID shared region
    float* base = (float*)d_ws;
    int*   flag = (int*)base;
    float* X   = base + 16;          // NE f32 residual (persistent)
    float* fQ  = X + NE;             // NE/2 floats (Qb)
    float* fK  = fQ + NE / 2;        // NE/2 floats (Kb)
    float* fV  = fK + NE / 2;        // NE/2 floats (Vt global, s-permuted)
    float* fH  = fV + NE / 2;        // NE/2 floats (Hb)
    float* fW  = fH + NE / 2;        // converted weights (contiguous)
    __bf16* Qb    = (__bf16*)fQ;
    __bf16* Kb    = (__bf16*)fK;
    __bf16* Vtg   = (__bf16*)fV;     // [ (b*8+h)*64 + d ][ s (permuted/64) ]
    __bf16* Hb    = (__bf16*)fH;
    __bf16* wqc = (__bf16*)fW;
    __bf16* wkc = wqc + 2 * EE * EE;
    __bf16* wvc = wkc + 2 * EE * EE;
    __bf16* W1c = wvc + 2 * EE * EE;
    __bf16* W2c = W1c + DFF_ * EE;
    float* MLl = (float*)(W2c + (size_t)EE * DFF_);   // KSPLIT*16*SS f32
    float* fO  = MLl + (size_t)KSPLIT * 16 * SS;
    __bf16* Opart = (__bf16*)fO;     // KSPLIT x 16 bh x 2048 x 64 bf16
    __bf16* MID   = (__bf16*)fO;     // NTOK*DFF bf16 (aliases dead Opart)

    // x -> X (f32) fused with layer-0 LN1 -> Hb; self-sniffs dtype
    cvt_ln<<<NTOK, 256, 0, stream>>>(x_in, X, g1, b1, Hb, flag);
    wcvt_all<<<1792, 256, 0, stream>>>(wq, wk, wv, W1, W2, wqc, flag);

    const dim3 gQKV(NTOK / 128, EE / 64, 3);       // 768 blocks = 3/CU exact
    const dim3 gF1 (NTOK / 128, DFF_ / 128, 1);    // 512 blocks
    const dim3 gF2 (NTOK / 128, EE / 128, 4);      // 512 blocks (split-K x4)
    const dim3 gAtt(SS / 128, BB * HH, KSPLIT);    // 512 blocks = 2/CU

    for (int l = 0; l < 2; ++l) {
        const size_t wo = (size_t)l * EE * EE, bo = (size_t)l * EE;
        if (l > 0)
            ln_kernel<<<NTOK, 256, 0, stream>>>(X, g1, b1, Hb, nullptr, flag);
        gemm_qkv<<<gQKV, 256, 0, stream>>>(Hb, wqc, wkc, wvc, bq, bk, bv,
            Qb, Kb, Vtg, wo, bo, flag);
        attn_mfma<<<gAtt, 256, 0, stream>>>(Qb, Kb, Vtg, mask, Opart, MLl);
        combine_ln<<<NTOK, 256, 0, stream>>>(Opart, MLl, g2, b2, X, Hb, flag);
        gemm_mfma<<<gF1, 256, 0, stream>>>(Hb, W1c, W1c, W1c, B1, B1, B1,
            MID, MID, MID, nullptr, NTOK, DFF_, EE, 1, 0, 0, flag);
        gemm_mfma<<<gF2, 256, 0, stream>>>(MID, W2c, W2c, W2c, B2, B2, B2,
            nullptr, nullptr, nullptr, X, NTOK, EE, DFF_, 2 | 4, 0, 0, flag);
    }
    ln_kernel<<<NTOK, 256, 0, stream>>>(X, gf, bfp, nullptr, d_out, flag);
}